// Round 8
// baseline (2602.869 us; speedup 1.0000x reference)
//
#include <hip/hip_runtime.h>
#include <math.h>

#define N_NODES 4096
#define WORDS   64
#define HID     256
#define VOCAB   50257
#define NCLASS  4
#define N_LEAF  2048
#define RNN_BLOCKS 256   // 1 block/CU -> all resident, spin-wait safe
#define NPB 16           // nodes per block (contiguous range)
#define FLAG_STRIDE 16   // one 64B line per flag

typedef _Float16 half2_t __attribute__((ext_vector_type(2)));

__device__ __forceinline__ float dot2f(half2_t a, half2_t b, float c) {
#if __has_builtin(__builtin_amdgcn_fdot2)
  return __builtin_amdgcn_fdot2(a, b, c, false);   // v_dot2_f32_f16
#else
  return c + (float)a.x * (float)b.x + (float)a.y * (float)b.y;
#endif
}

__device__ __forceinline__ half2_t f2h2(float f) {
  union { float f; half2_t h; } u; u.f = f; return u.h;
}

// ---------------------------------------------------------------- init flags
__global__ void init_flags_kernel(int* __restrict__ flags) {
  int i = blockIdx.x * blockDim.x + threadIdx.x;
  if (i < N_NODES * FLAG_STRIDE) flags[i] = 0;
}

// ---------------------------------------------------------------- E (HID,VOCAB) f32 -> ETh (VOCAB,HID) f16
__global__ void transpose_f16_kernel(const float* __restrict__ src, _Float16* __restrict__ dst,
                                     int R, int C) {
  __shared__ float tile[32][33];
  int c0 = blockIdx.x * 32, r0 = blockIdx.y * 32;
  int tx = threadIdx.x, ty = threadIdx.y;
#pragma unroll
  for (int j = 0; j < 32; j += 8) {
    int c = c0 + tx, r = r0 + ty + j;
    if (c < C) tile[ty + j][tx] = src[(size_t)r * C + c];
  }
  __syncthreads();
#pragma unroll
  for (int j = 0; j < 32; j += 8) {
    int c = c0 + ty + j, r = r0 + tx;
    if (c < C) dst[(size_t)c * R + r] = (_Float16)tile[tx][ty + j];
  }
}

// ---------------------------------------------------------------- pack U -> half2, layout Upk[(m*4+s)*8192 + j*256 + h]
// s in [0,4) = 64-wide k-slice; j in [0,32): pair (k = s*64+2j, s*64+2j+1) of U_m[h][k]
__global__ void __launch_bounds__(256) pack_u_kernel(
    const float* __restrict__ Uz, const float* __restrict__ Ur, const float* __restrict__ Uh,
    half2_t* __restrict__ Upk) {
  __shared__ float tile[64][259];
  int m = blockIdx.x >> 2, g = blockIdx.x & 3;
  const float* U = m == 0 ? Uz : (m == 1 ? Ur : Uh);
  int t = threadIdx.x;
  for (int r = 0; r < 64; ++r) tile[r][t] = U[(size_t)(g * 64 + r) * 256 + t];
  __syncthreads();
#pragma unroll
  for (int it = 0; it < 32; ++it) {
    int e = it * 256 + t;
    int hl = e & 63, kj = e >> 6, s = kj >> 5, j = kj & 31;
    half2_t v;
    v.x = (_Float16)tile[hl][s * 64 + 2 * j];
    v.y = (_Float16)tile[hl][s * 64 + 2 * j + 1];
    Upk[(size_t)(m * 4 + s) * 8192 + j * 256 + (g * 64 + hl)] = v;
  }
}

// ---------------------------------------------------------------- X[i,h] = sum_w ETh[tree[i,w], h]  (f16 ET, dword loads)
__global__ void gather_x_kernel(const int* __restrict__ tree, const half2_t* __restrict__ ETh2,
                                float* __restrict__ X, float* __restrict__ H,
                                half2_t* __restrict__ Hpk) {
  int i = blockIdx.x;
  int t = threadIdx.x;            // 128 threads; thread t covers h = 2t, 2t+1
  __shared__ int vs[WORDS];
  if (t < WORDS) vs[t] = tree[i * WORDS + t];
  __syncthreads();
  float ax = 0.f, ay = 0.f;
#pragma unroll 8
  for (int w = 0; w < WORDS; ++w) {
    half2_t e = ETh2[(size_t)vs[w] * (HID / 2) + t];
    ax += (float)e.x;
    ay += (float)e.y;
  }
  float2 v2; v2.x = ax; v2.y = ay;
  ((float2*)(X + (size_t)i * HID))[t] = v2;
  if (i == 0) {
    ((float2*)H)[t] = v2;                 // node 0 seed (fp32)
    half2_t hv; hv.x = (_Float16)ax; hv.y = (_Float16)ay;
    Hpk[t] = hv;                          // node 0 seed (packed fp16)
  }
}

// ---------------------------------------------------------------- A = X @ W^T for 3 weights
__global__ void __launch_bounds__(256) gemm3_kernel(
    const float* __restrict__ X,
    const float* __restrict__ W0, const float* __restrict__ W1, const float* __restrict__ W2,
    float* __restrict__ A0, float* __restrict__ A1, float* __restrict__ A2) {
  const float* W = blockIdx.z == 0 ? W0 : (blockIdx.z == 1 ? W1 : W2);
  float*       A = blockIdx.z == 0 ? A0 : (blockIdx.z == 1 ? A1 : A2);
  __shared__ float Xs[16][65];
  __shared__ float Ws[16][65];
  int tid = threadIdx.x;
  int m0 = blockIdx.x * 64, n0 = blockIdx.y * 64;
  int tm = (tid / 16) * 4, tn = (tid % 16) * 4;
  int lm = tid >> 2, lk = (tid & 3) * 4;
  float acc[4][4];
#pragma unroll
  for (int a = 0; a < 4; ++a)
#pragma unroll
    for (int b = 0; b < 4; ++b) acc[a][b] = 0.f;

  for (int k0 = 0; k0 < HID; k0 += 16) {
    float4 xv = *(const float4*)(X + (size_t)(m0 + lm) * HID + k0 + lk);
    Xs[lk + 0][lm] = xv.x; Xs[lk + 1][lm] = xv.y; Xs[lk + 2][lm] = xv.z; Xs[lk + 3][lm] = xv.w;
    float4 wv = *(const float4*)(W + (size_t)(n0 + lm) * HID + k0 + lk);
    Ws[lk + 0][lm] = wv.x; Ws[lk + 1][lm] = wv.y; Ws[lk + 2][lm] = wv.z; Ws[lk + 3][lm] = wv.w;
    __syncthreads();
#pragma unroll
    for (int k = 0; k < 16; ++k) {
      float xm[4], wn[4];
#pragma unroll
      for (int u = 0; u < 4; ++u) { xm[u] = Xs[k][tm + u]; wn[u] = Ws[k][tn + u]; }
#pragma unroll
      for (int a = 0; a < 4; ++a)
#pragma unroll
        for (int b = 0; b < 4; ++b) acc[a][b] = fmaf(xm[a], wn[b], acc[a][b]);
    }
    __syncthreads();
  }
#pragma unroll
  for (int a = 0; a < 4; ++a)
#pragma unroll
    for (int b = 0; b < 4; ++b)
      A[(size_t)(m0 + tm + a) * HID + n0 + tn + b] = acc[a][b];
}

// ---------------------------------------------------------------- persistent wavefront GRU scan
// Contiguous ranges: block b owns nodes [b*NPB, b*NPB+NPB). All computed rows stay in LDS, so
// in-range parents need no flag spin and no LLC round trip (the tree's early critical path is
// a near-chain of consecutive nodes). Cross-range parents use the R7 relaxed-agent protocol.
// Split-matrix registers: thread (h, ks): ks0 holds full-K Uz (128 half2) + Uh k-slice (64);
// ks1 holds full-K Ur + Uh k-slice. Phase-1 has no partial-sum reduction -> 3 barriers/node.
// All loops over U are FULLY unrolled (R6 lesson: partial unroll -> alloca -> LDS/scratch).
__global__ void
__attribute__((amdgpu_flat_work_group_size(512, 512), amdgpu_waves_per_eu(2, 2)))
rnn_kernel(
    const float* __restrict__ Az, const float* __restrict__ Ar, const float* __restrict__ Ah,
    const half2_t* __restrict__ Upk,
    const float* __restrict__ bz, const float* __restrict__ br, const float* __restrict__ bh,
    const int* __restrict__ edge, float* __restrict__ H, half2_t* __restrict__ Hpk,
    int* flags) {
  const int tid = threadIdx.x;
  const int h   = tid & (HID - 1);
  const int ks  = tid >> 8;            // 0..1
  const int base = blockIdx.x * NPB;

  __shared__ half2_t hpk_loc[(NPB + 1) * (HID / 2)];   // packed rows: NPB resident + 1 scratch
  __shared__ float   hf_loc[(NPB + 1) * HID];          // fp32 rows
  __shared__ half2_t rhp[HID / 2];
  __shared__ float   part[2 * HID];

  // one-time U load (full unroll -> SSA -> register file)
  half2_t um[128];   // Uz (ks0) or Ur (ks1), full K
  half2_t uhh[64];   // Uh, k-slice [ks*128, ks*128+128)
  {
    const half2_t* mb = Upk + (size_t)(ks ? 4 : 0) * 8192 + h;
#pragma unroll
    for (int j = 0; j < 128; ++j)
      um[j] = mb[(j >> 5) * 8192 + (j & 31) * 256];
    const half2_t* hb = Upk + (size_t)(8 + 2 * ks) * 8192 + h;
#pragma unroll
    for (int j = 0; j < 64; ++j)
      uhh[j] = hb[(j >> 5) * 8192 + (j & 31) * 256];
  }
  const float b1  = ks ? br[h] : bz[h];
  const float bhv = ks ? 0.f : bh[h];

  if (blockIdx.x == 0) {
    // preload node-0 row (written by gather) into slot 0; publish its flag
    if (tid < HID / 2) {
      unsigned raw = __hip_atomic_load((const unsigned*)&Hpk[tid], __ATOMIC_RELAXED,
                                       __HIP_MEMORY_SCOPE_AGENT);
      hpk_loc[tid] = __builtin_bit_cast(half2_t, raw);
    } else if (tid >= HID) {
      hf_loc[tid - HID] = __hip_atomic_load(&H[tid - HID], __ATOMIC_RELAXED,
                                            __HIP_MEMORY_SCOPE_AGENT);
    }
    if (tid == 0)
      __hip_atomic_store(&flags[0], 1, __ATOMIC_RELAXED, __HIP_MEMORY_SCOPE_AGENT);
  }
  __syncthreads();

  const int istart = base == 0 ? 1 : base;
  for (int i = istart; i < base + NPB; ++i) {
    const int p = edge[2 * i];   // parent, p < i
    // prefetch this node's A rows (independent of parent readiness)
    const float a1 = ks ? Ar[(size_t)i * HID + h] : Az[(size_t)i * HID + h];
    const float a2 = ks ? 0.f : Ah[(size_t)i * HID + h];

    int slot;
    if (p >= base) {
      slot = p - base;           // in-range: row already resident in LDS
    } else {
      slot = NPB;                // cross-range: spin + fill scratch slot
      long spin = 0;
      while (__hip_atomic_load(&flags[(size_t)p * FLAG_STRIDE], __ATOMIC_RELAXED,
                               __HIP_MEMORY_SCOPE_AGENT) == 0) {
        if (++spin > (1L << 25)) break;   // escape hatch (should never trigger)
      }
      if (tid < HID / 2) {
        unsigned raw = __hip_atomic_load((const unsigned*)&Hpk[(size_t)p * (HID / 2) + tid],
                                         __ATOMIC_RELAXED, __HIP_MEMORY_SCOPE_AGENT);
        hpk_loc[NPB * (HID / 2) + tid] = __builtin_bit_cast(half2_t, raw);
      } else if (tid >= HID) {
        hf_loc[NPB * HID + (tid - HID)] =
            __hip_atomic_load(&H[(size_t)p * HID + (tid - HID)], __ATOMIC_RELAXED,
                              __HIP_MEMORY_SCOPE_AGENT);
      }
      __syncthreads();
    }

    // phase 1: full-K dot of Uz (ks0) / Ur (ks1) against packed parent row
    float ac0 = 0.f, ac1 = 0.f, ac2 = 0.f, ac3 = 0.f;
    {
      const float4* phq = (const float4*)(hpk_loc + slot * (HID / 2));
#pragma unroll
      for (int q = 0; q < 32; ++q) {
        float4 blk = phq[q];
        ac0 = dot2f(um[4 * q + 0], f2h2(blk.x), ac0);
        ac1 = dot2f(um[4 * q + 1], f2h2(blk.y), ac1);
        ac2 = dot2f(um[4 * q + 2], f2h2(blk.z), ac2);
        ac3 = dot2f(um[4 * q + 3], f2h2(blk.w), ac3);
      }
    }
    const float phv = hf_loc[slot * HID + h];
    const float g = 1.f / (1.f + __expf(-(a1 + b1 + (ac0 + ac1) + (ac2 + ac3))));
    if (ks) {                    // r gate -> packed r*ph
      float rh = g * phv;
      float nb = __shfl_xor(rh, 1, 64);
      if ((h & 1) == 0) {
        half2_t v; v.x = (_Float16)rh; v.y = (_Float16)nb;
        rhp[h >> 1] = v;
      }
    }
    __syncthreads();   // B1

    // phase 2: Uh partial dots over this thread's k-slice
    float c0 = 0.f, c1 = 0.f;
    {
      const float4* rq = (const float4*)(rhp + ks * 64);
#pragma unroll
      for (int q = 0; q < 16; ++q) {
        float4 blk = rq[q];
        c0 = dot2f(uhh[4 * q + 0], f2h2(blk.x), c0);
        c1 = dot2f(uhh[4 * q + 1], f2h2(blk.y), c1);
        c0 = dot2f(uhh[4 * q + 2], f2h2(blk.z), c0);
        c1 = dot2f(uhh[4 * q + 3], f2h2(blk.w), c1);
      }
    }
    part[ks * HID + h] = c0 + c1;
    __syncthreads();   // B2

    if (ks == 0) {
      float ca = a2 + bhv + part[h] + part[HID + h];
      float c  = tanhf(ca);
      float hn = fmaf(g, phv, (1.f - g) * c);
      int sl = i - base;
      hf_loc[sl * HID + h] = hn;
      __hip_atomic_store(&H[(size_t)i * HID + h], hn, __ATOMIC_RELAXED,
                         __HIP_MEMORY_SCOPE_AGENT);
      float nb = __shfl_xor(hn, 1, 64);
      if ((h & 1) == 0) {
        half2_t v; v.x = (_Float16)hn; v.y = (_Float16)nb;
        hpk_loc[sl * (HID / 2) + (h >> 1)] = v;
        __hip_atomic_store((unsigned*)&Hpk[(size_t)i * (HID / 2) + (h >> 1)],
                           __builtin_bit_cast(unsigned, v),
                           __ATOMIC_RELAXED, __HIP_MEMORY_SCOPE_AGENT);
      }
    }
    __builtin_amdgcn_s_waitcnt(0);   // each wave drains its own store acks
    __syncthreads();   // B3: all waves' stores acked + LDS rows visible
    if (tid == 0)
      __hip_atomic_store(&flags[(size_t)i * FLAG_STRIDE], 1, __ATOMIC_RELAXED,
                         __HIP_MEMORY_SCOPE_AGENT);
  }
}

// ---------------------------------------------------------------- leaf max partial (64 blocks x 32 leaves)
__global__ void leafmax_kernel(const float* __restrict__ H, const int* __restrict__ leafs,
                               float* __restrict__ partial) {
  int b = blockIdx.x;
  int h = threadIdx.x;
  float m = -INFINITY;
#pragma unroll 4
  for (int j = 0; j < N_LEAF / 64; ++j) {
    int node = leafs[b * (N_LEAF / 64) + j];
    m = fmaxf(m, H[(size_t)node * HID + h]);
  }
  partial[b * HID + h] = m;
}

// ---------------------------------------------------------------- final: reduce partials, W_out, softmax, loss
__global__ void final_kernel(const float* __restrict__ partial, const float* __restrict__ W_out,
                             const float* __restrict__ b_out, const float* __restrict__ y,
                             float* __restrict__ out) {
  int h = threadIdx.x;
  float m = -INFINITY;
#pragma unroll 8
  for (int b = 0; b < 64; ++b) m = fmaxf(m, partial[b * HID + h]);
  __shared__ float fs[HID];
  __shared__ float red[HID];
  __shared__ float logit[NCLASS];
  fs[h] = m;
  __syncthreads();
  for (int c = 0; c < NCLASS; ++c) {
    red[h] = W_out[c * HID + h] * fs[h];
    __syncthreads();
    for (int s = HID / 2; s > 0; s >>= 1) {
      if (h < s) red[h] += red[h + s];
      __syncthreads();
    }
    if (h == 0) logit[c] = red[0] + b_out[c];
    __syncthreads();
  }
  if (h == 0) {
    float mx = logit[0];
    for (int c = 1; c < NCLASS; ++c) mx = fmaxf(mx, logit[c]);
    float e[NCLASS], s = 0.f;
    for (int c = 0; c < NCLASS; ++c) { e[c] = expf(logit[c] - mx); s += e[c]; }
    float loss = 0.f;
    for (int c = 0; c < NCLASS; ++c) {
      float p = e[c] / s;
      out[c] = p;
      float d = y[c] - p;
      loss += d * d;
    }
    out[NCLASS] = loss;
  }
}

// ---------------------------------------------------------------- launch
extern "C" void kernel_launch(void* const* d_in, const int* in_sizes, int n_in,
                              void* d_out, int out_size, void* d_ws, size_t ws_size,
                              hipStream_t stream) {
  const int*   tree = (const int*)d_in[0];
  const int*   edge = (const int*)d_in[1];
  const int*   leaf = (const int*)d_in[2];
  const float* y    = (const float*)d_in[3];
  const float* E    = (const float*)d_in[4];
  const float* Wz   = (const float*)d_in[5];
  const float* Uz   = (const float*)d_in[6];
  const float* bz   = (const float*)d_in[7];
  const float* Wr   = (const float*)d_in[8];
  const float* Ur   = (const float*)d_in[9];
  const float* br   = (const float*)d_in[10];
  const float* Wh   = (const float*)d_in[11];
  const float* Uh   = (const float*)d_in[12];
  const float* bh   = (const float*)d_in[13];
  const float* Wout = (const float*)d_in[14];
  const float* bout = (const float*)d_in[15];
  float* out = (float*)d_out;

  char* base = (char*)d_ws;
  size_t b = 0;
  _Float16* ETh = (_Float16*)(base + b); b += (size_t)VOCAB * HID * 2;      // 25.7 MB
  b = (b + 255) & ~(size_t)255;
  half2_t* Upk = (half2_t*)(base + b); b += (size_t)3 * 4 * 8192 * 4;       // 98304 half2
  half2_t* Hpk = (half2_t*)(base + b); b += (size_t)N_NODES * (HID / 2) * 4;
  float* X   = (float*)(base + b); b += (size_t)N_NODES * HID * 4;
  float* Az  = (float*)(base + b); b += (size_t)N_NODES * HID * 4;
  float* Ar  = (float*)(base + b); b += (size_t)N_NODES * HID * 4;
  float* Ah  = (float*)(base + b); b += (size_t)N_NODES * HID * 4;
  float* H   = (float*)(base + b); b += (size_t)N_NODES * HID * 4;
  float* partial = (float*)(base + b); b += (size_t)64 * HID * 4;
  int*   flags   = (int*)(base + b);   b += (size_t)N_NODES * FLAG_STRIDE * 4;

  init_flags_kernel<<<(N_NODES * FLAG_STRIDE + 255) / 256, 256, 0, stream>>>(flags);
  transpose_f16_kernel<<<dim3((VOCAB + 31) / 32, HID / 32), dim3(32, 8), 0, stream>>>(E, ETh, HID, VOCAB);
  pack_u_kernel<<<12, 256, 0, stream>>>(Uz, Ur, Uh, Upk);
  gather_x_kernel<<<N_NODES, 128, 0, stream>>>(tree, (const half2_t*)ETh, X, H, Hpk);
  gemm3_kernel<<<dim3(N_NODES / 64, HID / 64, 3), 256, 0, stream>>>(X, Wz, Wr, Wh, Az, Ar, Ah);
  rnn_kernel<<<RNN_BLOCKS, 512, 0, stream>>>(Az, Ar, Ah, Upk, bz, br, bh, edge, H, Hpk, flags);
  leafmax_kernel<<<64, HID, 0, stream>>>(H, leaf, partial);
  final_kernel<<<1, HID, 0, stream>>>(partial, Wout, bout, y, out);
}

// Round 9
// 559.925 us; speedup vs baseline: 4.6486x; 4.6486x over previous
//
#include <hip/hip_runtime.h>
#include <math.h>

#define N_NODES 4096
#define WORDS   64
#define HID     256
#define VOCAB   50257
#define NCLASS  4
#define N_LEAF  2048
#define RNN_BLOCKS 256     // 1 block/CU -> all resident, spin-wait safe
#define POISON 0x7FFF7FFFu // half2 (NaN,NaN); real h values never hit this pattern

typedef _Float16 half2_t __attribute__((ext_vector_type(2)));

__device__ __forceinline__ float dot2f(half2_t a, half2_t b, float c) {
#if __has_builtin(__builtin_amdgcn_fdot2)
  return __builtin_amdgcn_fdot2(a, b, c, false);   // v_dot2_f32_f16
#else
  return c + (float)a.x * (float)b.x + (float)a.y * (float)b.y;
#endif
}

__device__ __forceinline__ half2_t f2h2(float f) {
  union { float f; half2_t h; } u; u.f = f; return u.h;
}

// ---------------------------------------------------------------- poison Hpk (the handoff medium)
__global__ void poison_hpk_kernel(unsigned* __restrict__ HpkU) {
  int i = blockIdx.x * blockDim.x + threadIdx.x;
  if (i < N_NODES * (HID / 2)) HpkU[i] = POISON;
}

// ---------------------------------------------------------------- E (HID,VOCAB) f32 -> ETh (VOCAB,HID) f16
__global__ void transpose_f16_kernel(const float* __restrict__ src, _Float16* __restrict__ dst,
                                     int R, int C) {
  __shared__ float tile[32][33];
  int c0 = blockIdx.x * 32, r0 = blockIdx.y * 32;
  int tx = threadIdx.x, ty = threadIdx.y;
#pragma unroll
  for (int j = 0; j < 32; j += 8) {
    int c = c0 + tx, r = r0 + ty + j;
    if (c < C) tile[ty + j][tx] = src[(size_t)r * C + c];
  }
  __syncthreads();
#pragma unroll
  for (int j = 0; j < 32; j += 8) {
    int c = c0 + ty + j, r = r0 + tx;
    if (c < C) dst[(size_t)c * R + r] = (_Float16)tile[tx][ty + j];
  }
}

// ---------------------------------------------------------------- pack U -> half2, layout Upk[(m*4+s)*8192 + j*256 + h]
// s in [0,4) = 64-wide k-slice; j in [0,32): pair (k = s*64+2j, s*64+2j+1) of U_m[h][k]
__global__ void __launch_bounds__(256) pack_u_kernel(
    const float* __restrict__ Uz, const float* __restrict__ Ur, const float* __restrict__ Uh,
    half2_t* __restrict__ Upk) {
  __shared__ float tile[64][259];
  int m = blockIdx.x >> 2, g = blockIdx.x & 3;
  const float* U = m == 0 ? Uz : (m == 1 ? Ur : Uh);
  int t = threadIdx.x;
  for (int r = 0; r < 64; ++r) tile[r][t] = U[(size_t)(g * 64 + r) * 256 + t];
  __syncthreads();
#pragma unroll
  for (int it = 0; it < 32; ++it) {
    int e = it * 256 + t;
    int hl = e & 63, kj = e >> 6, s = kj >> 5, j = kj & 31;
    half2_t v;
    v.x = (_Float16)tile[hl][s * 64 + 2 * j];
    v.y = (_Float16)tile[hl][s * 64 + 2 * j + 1];
    Upk[(size_t)(m * 4 + s) * 8192 + j * 256 + (g * 64 + hl)] = v;
  }
}

// ---------------------------------------------------------------- X[i,h] = sum_w ETh[tree[i,w], h]
__global__ void gather_x_kernel(const int* __restrict__ tree, const half2_t* __restrict__ ETh2,
                                float* __restrict__ X, float* __restrict__ H,
                                half2_t* __restrict__ Hpk) {
  int i = blockIdx.x;
  int t = threadIdx.x;            // 128 threads; thread t covers h = 2t, 2t+1
  __shared__ int vs[WORDS];
  if (t < WORDS) vs[t] = tree[i * WORDS + t];
  __syncthreads();
  float ax = 0.f, ay = 0.f;
#pragma unroll 8
  for (int w = 0; w < WORDS; ++w) {
    half2_t e = ETh2[(size_t)vs[w] * (HID / 2) + t];
    ax += (float)e.x;
    ay += (float)e.y;
  }
  float2 v2; v2.x = ax; v2.y = ay;
  ((float2*)(X + (size_t)i * HID))[t] = v2;
  if (i == 0) {
    ((float2*)H)[t] = v2;                 // node 0 fp32 (for leafmax)
    half2_t hv; hv.x = (_Float16)ax; hv.y = (_Float16)ay;
    Hpk[t] = hv;                          // node 0 packed row (un-poisons it)
  }
}

// ---------------------------------------------------------------- A = X @ W^T for 3 weights
__global__ void __launch_bounds__(256) gemm3_kernel(
    const float* __restrict__ X,
    const float* __restrict__ W0, const float* __restrict__ W1, const float* __restrict__ W2,
    float* __restrict__ A0, float* __restrict__ A1, float* __restrict__ A2) {
  const float* W = blockIdx.z == 0 ? W0 : (blockIdx.z == 1 ? W1 : W2);
  float*       A = blockIdx.z == 0 ? A0 : (blockIdx.z == 1 ? A1 : A2);
  __shared__ float Xs[16][65];
  __shared__ float Ws[16][65];
  int tid = threadIdx.x;
  int m0 = blockIdx.x * 64, n0 = blockIdx.y * 64;
  int tm = (tid / 16) * 4, tn = (tid % 16) * 4;
  int lm = tid >> 2, lk = (tid & 3) * 4;
  float acc[4][4];
#pragma unroll
  for (int a = 0; a < 4; ++a)
#pragma unroll
    for (int b = 0; b < 4; ++b) acc[a][b] = 0.f;

  for (int k0 = 0; k0 < HID; k0 += 16) {
    float4 xv = *(const float4*)(X + (size_t)(m0 + lm) * HID + k0 + lk);
    Xs[lk + 0][lm] = xv.x; Xs[lk + 1][lm] = xv.y; Xs[lk + 2][lm] = xv.z; Xs[lk + 3][lm] = xv.w;
    float4 wv = *(const float4*)(W + (size_t)(n0 + lm) * HID + k0 + lk);
    Ws[lk + 0][lm] = wv.x; Ws[lk + 1][lm] = wv.y; Ws[lk + 2][lm] = wv.z; Ws[lk + 3][lm] = wv.w;
    __syncthreads();
#pragma unroll
    for (int k = 0; k < 16; ++k) {
      float xm[4], wn[4];
#pragma unroll
      for (int u = 0; u < 4; ++u) { xm[u] = Xs[k][tm + u]; wn[u] = Ws[k][tn + u]; }
#pragma unroll
      for (int a = 0; a < 4; ++a)
#pragma unroll
        for (int b = 0; b < 4; ++b) acc[a][b] = fmaf(xm[a], wn[b], acc[a][b]);
    }
    __syncthreads();
  }
#pragma unroll
  for (int a = 0; a < 4; ++a)
#pragma unroll
    for (int b = 0; b < 4; ++b)
      A[(size_t)(m0 + tm + a) * HID + n0 + tn + b] = acc[a][b];
}

// ---------------------------------------------------------------- persistent wavefront GRU scan (block-cyclic)
// Pollable-row handoff: producer's relaxed-agent stores of the packed fp16 row ARE the signal;
// 128 consumer threads each poll their own dword until != POISON. No flags, no s_waitcnt drain,
// no publish barrier -> saves ~one LLC round trip + drain per hop vs R7.
// Split-matrix registers (R7): ks0 holds full-K Uz + Uh k-slice; ks1 holds full-K Ur + Uh k-slice.
// All U loops FULLY unrolled (R6 lesson: partial unroll -> alloca -> LDS/scratch catastrophe).
__global__ void
__attribute__((amdgpu_flat_work_group_size(512, 512), amdgpu_waves_per_eu(2, 2)))
rnn_kernel(
    const float* __restrict__ Az, const float* __restrict__ Ar, const float* __restrict__ Ah,
    const half2_t* __restrict__ Upk,
    const float* __restrict__ bz, const float* __restrict__ br, const float* __restrict__ bh,
    const int* __restrict__ edge, float* __restrict__ H, unsigned* HpkU) {
  const int tid = threadIdx.x;
  const int h   = tid & (HID - 1);
  const int ks  = tid >> 8;            // 0..1
  __shared__ half2_t php[HID / 2];
  __shared__ half2_t rhp[HID / 2];
  __shared__ float   part[2 * HID];

  // one-time U load (full unroll -> SSA -> register file)
  half2_t um[128];   // Uz (ks0) or Ur (ks1), full K
  half2_t uhh[64];   // Uh, k-slice [ks*128, ks*128+128)
  {
    const half2_t* mb = Upk + (size_t)(ks ? 4 : 0) * 8192 + h;
#pragma unroll
    for (int j = 0; j < 128; ++j)
      um[j] = mb[(j >> 5) * 8192 + (j & 31) * 256];
    const half2_t* hb = Upk + (size_t)(8 + 2 * ks) * 8192 + h;
#pragma unroll
    for (int j = 0; j < 64; ++j)
      uhh[j] = hb[(j >> 5) * 8192 + (j & 31) * 256];
  }
  const float b1  = ks ? br[h] : bz[h];
  const float bhv = ks ? 0.f : bh[h];

  for (int i = blockIdx.x; i < N_NODES; i += RNN_BLOCKS) {
    if (i == 0) continue;        // node 0 pre-seeded by gather (uniform within block 0)
    const int p = edge[2 * i];   // parent, p < i
    // A-row loads issued before the poll; they complete while waiting
    const float a1 = ks ? Ar[(size_t)i * HID + h] : Az[(size_t)i * HID + h];
    const float a2 = ks ? 0.f : Ah[(size_t)i * HID + h];

    if (tid < HID / 2) {
      unsigned v = __hip_atomic_load(&HpkU[(size_t)p * (HID / 2) + tid],
                                     __ATOMIC_RELAXED, __HIP_MEMORY_SCOPE_AGENT);
      long spin = 0;
      while (v == POISON) {
        if (++spin > (1L << 26)) break;   // escape hatch (should never trigger)
        v = __hip_atomic_load(&HpkU[(size_t)p * (HID / 2) + tid],
                              __ATOMIC_RELAXED, __HIP_MEMORY_SCOPE_AGENT);
      }
      php[tid] = __builtin_bit_cast(half2_t, v);
    }
    __syncthreads();   // B0: packed parent row resident in LDS

    // parent element for this h, decoded from fp16 row
    half2_t ph2 = php[h >> 1];
    const float phv = (float)((h & 1) ? ph2.y : ph2.x);

    // phase 1: full-K dot of Uz (ks0) / Ur (ks1) against packed parent row
    float ac0 = 0.f, ac1 = 0.f, ac2 = 0.f, ac3 = 0.f;
    {
      const float4* phq = (const float4*)php;
#pragma unroll
      for (int q = 0; q < 32; ++q) {
        float4 blk = phq[q];
        ac0 = dot2f(um[4 * q + 0], f2h2(blk.x), ac0);
        ac1 = dot2f(um[4 * q + 1], f2h2(blk.y), ac1);
        ac2 = dot2f(um[4 * q + 2], f2h2(blk.z), ac2);
        ac3 = dot2f(um[4 * q + 3], f2h2(blk.w), ac3);
      }
    }
    const float g = 1.f / (1.f + __expf(-(a1 + b1 + (ac0 + ac1) + (ac2 + ac3))));
    if (ks) {                    // r gate -> packed r*ph
      float rh = g * phv;
      float nb = __shfl_xor(rh, 1, 64);
      if ((h & 1) == 0) {
        half2_t v; v.x = (_Float16)rh; v.y = (_Float16)nb;
        rhp[h >> 1] = v;
      }
    }
    __syncthreads();   // B1

    // phase 2: Uh partial dots over this thread's k-slice
    float c0 = 0.f, c1 = 0.f;
    {
      const float4* rq = (const float4*)(rhp + ks * 64);
#pragma unroll
      for (int q = 0; q < 16; ++q) {
        float4 blk = rq[q];
        c0 = dot2f(uhh[4 * q + 0], f2h2(blk.x), c0);
        c1 = dot2f(uhh[4 * q + 1], f2h2(blk.y), c1);
        c0 = dot2f(uhh[4 * q + 2], f2h2(blk.z), c0);
        c1 = dot2f(uhh[4 * q + 3], f2h2(blk.w), c1);
      }
    }
    part[ks * HID + h] = c0 + c1;
    __syncthreads();   // B2

    if (ks == 0) {
      float ca = a2 + bhv + part[h] + part[HID + h];
      float c  = tanhf(ca);
      float hn = fmaf(g, phv, (1.f - g) * c);
      H[(size_t)i * HID + h] = hn;        // plain store, read by leafmax next kernel
      float nb = __shfl_xor(hn, 1, 64);
      if ((h & 1) == 0) {
        half2_t v; v.x = (_Float16)hn; v.y = (_Float16)nb;
        __hip_atomic_store(&HpkU[(size_t)i * (HID / 2) + (h >> 1)],
                           __builtin_bit_cast(unsigned, v),
                           __ATOMIC_RELAXED, __HIP_MEMORY_SCOPE_AGENT);
      }
    }
    // no publish barrier, no waitcnt, no flag: the row stores are the signal
  }
}

// ---------------------------------------------------------------- leaf max partial (64 blocks x 32 leaves)
__global__ void leafmax_kernel(const float* __restrict__ H, const int* __restrict__ leafs,
                               float* __restrict__ partial) {
  int b = blockIdx.x;
  int h = threadIdx.x;
  float m = -INFINITY;
#pragma unroll 4
  for (int j = 0; j < N_LEAF / 64; ++j) {
    int node = leafs[b * (N_LEAF / 64) + j];
    m = fmaxf(m, H[(size_t)node * HID + h]);
  }
  partial[b * HID + h] = m;
}

// ---------------------------------------------------------------- final: reduce partials, W_out, softmax, loss
__global__ void final_kernel(const float* __restrict__ partial, const float* __restrict__ W_out,
                             const float* __restrict__ b_out, const float* __restrict__ y,
                             float* __restrict__ out) {
  int h = threadIdx.x;
  float m = -INFINITY;
#pragma unroll 8
  for (int b = 0; b < 64; ++b) m = fmaxf(m, partial[b * HID + h]);
  __shared__ float fs[HID];
  __shared__ float red[HID];
  __shared__ float logit[NCLASS];
  fs[h] = m;
  __syncthreads();
  for (int c = 0; c < NCLASS; ++c) {
    red[h] = W_out[c * HID + h] * fs[h];
    __syncthreads();
    for (int s = HID / 2; s > 0; s >>= 1) {
      if (h < s) red[h] += red[h + s];
      __syncthreads();
    }
    if (h == 0) logit[c] = red[0] + b_out[c];
    __syncthreads();
  }
  if (h == 0) {
    float mx = logit[0];
    for (int c = 1; c < NCLASS; ++c) mx = fmaxf(mx, logit[c]);
    float e[NCLASS], s = 0.f;
    for (int c = 0; c < NCLASS; ++c) { e[c] = expf(logit[c] - mx); s += e[c]; }
    float loss = 0.f;
    for (int c = 0; c < NCLASS; ++c) {
      float p = e[c] / s;
      out[c] = p;
      float d = y[c] - p;
      loss += d * d;
    }
    out[NCLASS] = loss;
  }
}

// ---------------------------------------------------------------- launch
extern "C" void kernel_launch(void* const* d_in, const int* in_sizes, int n_in,
                              void* d_out, int out_size, void* d_ws, size_t ws_size,
                              hipStream_t stream) {
  const int*   tree = (const int*)d_in[0];
  const int*   edge = (const int*)d_in[1];
  const int*   leaf = (const int*)d_in[2];
  const float* y    = (const float*)d_in[3];
  const float* E    = (const float*)d_in[4];
  const float* Wz   = (const float*)d_in[5];
  const float* Uz   = (const float*)d_in[6];
  const float* bz   = (const float*)d_in[7];
  const float* Wr   = (const float*)d_in[8];
  const float* Ur   = (const float*)d_in[9];
  const float* br   = (const float*)d_in[10];
  const float* Wh   = (const float*)d_in[11];
  const float* Uh   = (const float*)d_in[12];
  const float* bh   = (const float*)d_in[13];
  const float* Wout = (const float*)d_in[14];
  const float* bout = (const float*)d_in[15];
  float* out = (float*)d_out;

  char* base = (char*)d_ws;
  size_t b = 0;
  _Float16* ETh = (_Float16*)(base + b); b += (size_t)VOCAB * HID * 2;      // 25.7 MB
  b = (b + 255) & ~(size_t)255;
  half2_t* Upk = (half2_t*)(base + b); b += (size_t)3 * 4 * 8192 * 4;       // 98304 half2
  half2_t* Hpk = (half2_t*)(base + b); b += (size_t)N_NODES * (HID / 2) * 4;
  float* X   = (float*)(base + b); b += (size_t)N_NODES * HID * 4;
  float* Az  = (float*)(base + b); b += (size_t)N_NODES * HID * 4;
  float* Ar  = (float*)(base + b); b += (size_t)N_NODES * HID * 4;
  float* Ah  = (float*)(base + b); b += (size_t)N_NODES * HID * 4;
  float* H   = (float*)(base + b); b += (size_t)N_NODES * HID * 4;
  float* partial = (float*)(base + b); b += (size_t)64 * HID * 4;

  poison_hpk_kernel<<<(N_NODES * (HID / 2) + 255) / 256, 256, 0, stream>>>((unsigned*)Hpk);
  transpose_f16_kernel<<<dim3((VOCAB + 31) / 32, HID / 32), dim3(32, 8), 0, stream>>>(E, ETh, HID, VOCAB);
  pack_u_kernel<<<12, 256, 0, stream>>>(Uz, Ur, Uh, Upk);
  gather_x_kernel<<<N_NODES, 128, 0, stream>>>(tree, (const half2_t*)ETh, X, H, Hpk);
  gemm3_kernel<<<dim3(N_NODES / 64, HID / 64, 3), 256, 0, stream>>>(X, Wz, Wr, Wh, Az, Ar, Ah);
  rnn_kernel<<<RNN_BLOCKS, 512, 0, stream>>>(Az, Ar, Ah, Upk, bz, br, bh, edge, H, (unsigned*)Hpk);
  leafmax_kernel<<<64, HID, 0, stream>>>(H, leaf, partial);
  final_kernel<<<1, HID, 0, stream>>>(partial, Wout, bout, y, out);
}

// Round 11
// 534.601 us; speedup vs baseline: 4.8688x; 1.0474x over previous
//
#include <hip/hip_runtime.h>
#include <math.h>

#define N_NODES 4096
#define WORDS   64
#define HID     256
#define VOCAB   50257
#define NCLASS  4
#define N_LEAF  2048
#define RNN_BLOCKS 256     // 1 block/CU -> all resident, spin-wait safe
#define POISON 0x7FFF7FFFu // half2 (NaN,NaN); finite packed rows never match

typedef _Float16 half2_t __attribute__((ext_vector_type(2)));

__device__ __forceinline__ float dot2f(half2_t a, half2_t b, float c) {
#if __has_builtin(__builtin_amdgcn_fdot2)
  return __builtin_amdgcn_fdot2(a, b, c, false);   // v_dot2_f32_f16
#else
  return c + (float)a.x * (float)b.x + (float)a.y * (float)b.y;
#endif
}

__device__ __forceinline__ half2_t f2h2(float f) {
  union { float f; half2_t h; } u; u.f = f; return u.h;
}

__device__ __forceinline__ float fast_rcp(float x) { return __builtin_amdgcn_rcpf(x); }
__device__ __forceinline__ float fast_sigmoid(float x) {        // rcp-based, no IEEE div seq
  return fast_rcp(1.f + __expf(-x));
}
__device__ __forceinline__ float fast_tanh(float x) {           // 1 - 2/(e^{2x}+1); saturates to +-1
  return 1.f - 2.f * fast_rcp(1.f + __expf(2.f * x));
}
__device__ __forceinline__ half2_t pkrtz(float a, float b) {    // single v_cvt_pkrtz_f16_f32
#if __has_builtin(__builtin_amdgcn_cvt_pkrtz)
  return __builtin_bit_cast(half2_t, __builtin_amdgcn_cvt_pkrtz(a, b));
#else
  half2_t v; v.x = (_Float16)a; v.y = (_Float16)b; return v;
#endif
}

// ---------------------------------------------------------------- poison Hpk (the handoff medium)
__global__ void poison_hpk_kernel(unsigned* __restrict__ HpkU) {
  int i = blockIdx.x * blockDim.x + threadIdx.x;
  if (i < N_NODES * (HID / 2)) HpkU[i] = POISON;
}

// ---------------------------------------------------------------- E (HID,VOCAB) f32 -> ETh (VOCAB,HID) f16
__global__ void transpose_f16_kernel(const float* __restrict__ src, _Float16* __restrict__ dst,
                                     int R, int C) {
  __shared__ float tile[32][33];
  int c0 = blockIdx.x * 32, r0 = blockIdx.y * 32;
  int tx = threadIdx.x, ty = threadIdx.y;
#pragma unroll
  for (int j = 0; j < 32; j += 8) {
    int c = c0 + tx, r = r0 + ty + j;
    if (c < C) tile[ty + j][tx] = src[(size_t)r * C + c];
  }
  __syncthreads();
#pragma unroll
  for (int j = 0; j < 32; j += 8) {
    int c = c0 + ty + j, r = r0 + tx;
    if (c < C) dst[(size_t)c * R + r] = (_Float16)tile[tx][ty + j];
  }
}

// ---------------------------------------------------------------- pack U -> half2, layout Upk[(m*4+s)*8192 + j*256 + h]
__global__ void __launch_bounds__(256) pack_u_kernel(
    const float* __restrict__ Uz, const float* __restrict__ Ur, const float* __restrict__ Uh,
    half2_t* __restrict__ Upk) {
  __shared__ float tile[64][259];
  int m = blockIdx.x >> 2, g = blockIdx.x & 3;
  const float* U = m == 0 ? Uz : (m == 1 ? Ur : Uh);
  int t = threadIdx.x;
  for (int r = 0; r < 64; ++r) tile[r][t] = U[(size_t)(g * 64 + r) * 256 + t];
  __syncthreads();
#pragma unroll
  for (int it = 0; it < 32; ++it) {
    int e = it * 256 + t;
    int hl = e & 63, kj = e >> 6, s = kj >> 5, j = kj & 31;
    half2_t v;
    v.x = (_Float16)tile[hl][s * 64 + 2 * j];
    v.y = (_Float16)tile[hl][s * 64 + 2 * j + 1];
    Upk[(size_t)(m * 4 + s) * 8192 + j * 256 + (g * 64 + hl)] = v;
  }
}

// ---------------------------------------------------------------- X[i,h] = sum_w ETh[tree[i,w], h]
__global__ void gather_x_kernel(const int* __restrict__ tree, const half2_t* __restrict__ ETh2,
                                float* __restrict__ X, float* __restrict__ H,
                                half2_t* __restrict__ Hpk) {
  int i = blockIdx.x;
  int t = threadIdx.x;            // 128 threads; thread t covers h = 2t, 2t+1
  __shared__ int vs[WORDS];
  if (t < WORDS) vs[t] = tree[i * WORDS + t];
  __syncthreads();
  float ax = 0.f, ay = 0.f;
#pragma unroll 8
  for (int w = 0; w < WORDS; ++w) {
    half2_t e = ETh2[(size_t)vs[w] * (HID / 2) + t];
    ax += (float)e.x;
    ay += (float)e.y;
  }
  float2 v2; v2.x = ax; v2.y = ay;
  ((float2*)(X + (size_t)i * HID))[t] = v2;
  if (i == 0) {
    ((float2*)H)[t] = v2;                 // node 0 fp32 (for leafmax)
    half2_t hv; hv.x = (_Float16)ax; hv.y = (_Float16)ay;
    Hpk[t] = hv;                          // node 0 packed row (un-poisons it)
  }
}

// ---------------------------------------------------------------- A = X @ W^T for 3 weights
__global__ void __launch_bounds__(256) gemm3_kernel(
    const float* __restrict__ X,
    const float* __restrict__ W0, const float* __restrict__ W1, const float* __restrict__ W2,
    float* __restrict__ A0, float* __restrict__ A1, float* __restrict__ A2) {
  const float* W = blockIdx.z == 0 ? W0 : (blockIdx.z == 1 ? W1 : W2);
  float*       A = blockIdx.z == 0 ? A0 : (blockIdx.z == 1 ? A1 : A2);
  __shared__ float Xs[16][65];
  __shared__ float Ws[16][65];
  int tid = threadIdx.x;
  int m0 = blockIdx.x * 64, n0 = blockIdx.y * 64;
  int tm = (tid / 16) * 4, tn = (tid % 16) * 4;
  int lm = tid >> 2, lk = (tid & 3) * 4;
  float acc[4][4];
#pragma unroll
  for (int a = 0; a < 4; ++a)
#pragma unroll
    for (int b = 0; b < 4; ++b) acc[a][b] = 0.f;

  for (int k0 = 0; k0 < HID; k0 += 16) {
    float4 xv = *(const float4*)(X + (size_t)(m0 + lm) * HID + k0 + lk);
    Xs[lk + 0][lm] = xv.x; Xs[lk + 1][lm] = xv.y; Xs[lk + 2][lm] = xv.z; Xs[lk + 3][lm] = xv.w;
    float4 wv = *(const float4*)(W + (size_t)(n0 + lm) * HID + k0 + lk);
    Ws[lk + 0][lm] = wv.x; Ws[lk + 1][lm] = wv.y; Ws[lk + 2][lm] = wv.z; Ws[lk + 3][lm] = wv.w;
    __syncthreads();
#pragma unroll
    for (int k = 0; k < 16; ++k) {
      float xm[4], wn[4];
#pragma unroll
      for (int u = 0; u < 4; ++u) { xm[u] = Xs[k][tm + u]; wn[u] = Ws[k][tn + u]; }
#pragma unroll
      for (int a = 0; a < 4; ++a)
#pragma unroll
        for (int b = 0; b < 4; ++b) acc[a][b] = fmaf(xm[a], wn[b], acc[a][b]);
    }
    __syncthreads();
  }
#pragma unroll
  for (int a = 0; a < 4; ++a)
#pragma unroll
    for (int b = 0; b < 4; ++b)
      A[(size_t)(m0 + tm + a) * HID + n0 + tn + b] = acc[a][b];
}

// ---------------------------------------------------------------- persistent wavefront GRU scan (block-cyclic)
// R9 protocol (pollable rows, no flags/fences) + R10 fast epilogue: the serial tail between the
// last dot and the Hpk store is the handoff-critical chain, so tanh/sigmoid use __expf +
// v_rcp_f32 (no libm tanhf, no IEEE div sequence), packing is one v_cvt_pkrtz_f16_f32, and the
// Hpk (handoff) store issues before the fp32 H store.
// All U loops FULLY unrolled (R6 lesson: partial unroll -> alloca -> LDS/scratch catastrophe).
__global__ void
__attribute__((amdgpu_flat_work_group_size(512, 512), amdgpu_waves_per_eu(2, 2)))
rnn_kernel(
    const float* __restrict__ Az, const float* __restrict__ Ar, const float* __restrict__ Ah,
    const half2_t* __restrict__ Upk,
    const float* __restrict__ bz, const float* __restrict__ br, const float* __restrict__ bh,
    const int* __restrict__ edge, float* __restrict__ H, unsigned* HpkU) {
  const int tid = threadIdx.x;
  const int h   = tid & (HID - 1);
  const int ks  = tid >> 8;            // 0..1
  __shared__ half2_t php[HID / 2];
  __shared__ half2_t rhp[HID / 2];
  __shared__ float   part[2 * HID];

  // one-time U load (full unroll -> SSA -> register file)
  half2_t um[128];   // Uz (ks0) or Ur (ks1), full K
  half2_t uhh[64];   // Uh, k-slice [ks*128, ks*128+128)
  {
    const half2_t* mb = Upk + (size_t)(ks ? 4 : 0) * 8192 + h;
#pragma unroll
    for (int j = 0; j < 128; ++j)
      um[j] = mb[(j >> 5) * 8192 + (j & 31) * 256];
    const half2_t* hb = Upk + (size_t)(8 + 2 * ks) * 8192 + h;
#pragma unroll
    for (int j = 0; j < 64; ++j)
      uhh[j] = hb[(j >> 5) * 8192 + (j & 31) * 256];
  }
  const float b1  = ks ? br[h] : bz[h];
  const float bhv = ks ? 0.f : bh[h];

  const int istart = blockIdx.x == 0 ? RNN_BLOCKS : blockIdx.x;  // node 0 pre-seeded by gather
  for (int i = istart; i < N_NODES; i += RNN_BLOCKS) {
    const int p = edge[2 * i];   // parent, p < i
    // A-row loads issued before the poll; they complete while waiting
    const float a1 = ks ? Ar[(size_t)i * HID + h] : Az[(size_t)i * HID + h];
    const float a2 = ks ? 0.f : Ah[(size_t)i * HID + h];

    if (tid < HID / 2) {
      unsigned v = __hip_atomic_load(&HpkU[(size_t)p * (HID / 2) + tid],
                                     __ATOMIC_RELAXED, __HIP_MEMORY_SCOPE_AGENT);
      long spin = 0;
      while (v == POISON) {
        if (++spin > (1L << 26)) break;   // escape hatch (should never trigger)
        v = __hip_atomic_load(&HpkU[(size_t)p * (HID / 2) + tid],
                              __ATOMIC_RELAXED, __HIP_MEMORY_SCOPE_AGENT);
      }
      php[tid] = __builtin_bit_cast(half2_t, v);
    }
    __syncthreads();   // B0: packed parent row resident in LDS

    // parent element for this h, decoded from fp16 row
    half2_t ph2 = php[h >> 1];
    const float phv = (float)((h & 1) ? ph2.y : ph2.x);

    // phase 1: full-K dot of Uz (ks0) / Ur (ks1) against packed parent row
    float ac0 = a1 + b1, ac1 = 0.f, ac2 = 0.f, ac3 = 0.f;
    {
      const float4* phq = (const float4*)php;
#pragma unroll
      for (int q = 0; q < 32; ++q) {
        float4 blk = phq[q];
        ac0 = dot2f(um[4 * q + 0], f2h2(blk.x), ac0);
        ac1 = dot2f(um[4 * q + 1], f2h2(blk.y), ac1);
        ac2 = dot2f(um[4 * q + 2], f2h2(blk.z), ac2);
        ac3 = dot2f(um[4 * q + 3], f2h2(blk.w), ac3);
      }
    }
    const float g = fast_sigmoid((ac0 + ac1) + (ac2 + ac3));
    if (ks) {                    // r gate -> packed r*ph
      float rh = g * phv;
      float nb = __shfl_xor(rh, 1, 64);
      if ((h & 1) == 0) rhp[h >> 1] = pkrtz(rh, nb);
    }
    __syncthreads();   // B1

    // phase 2: Uh partial dots over this thread's k-slice
    float c0 = 0.f, c1 = 0.f;
    {
      const float4* rq = (const float4*)(rhp + ks * 64);
#pragma unroll
      for (int q = 0; q < 16; ++q) {
        float4 blk = rq[q];
        c0 = dot2f(uhh[4 * q + 0], f2h2(blk.x), c0);
        c1 = dot2f(uhh[4 * q + 1], f2h2(blk.y), c1);
        c0 = dot2f(uhh[4 * q + 2], f2h2(blk.z), c0);
        c1 = dot2f(uhh[4 * q + 3], f2h2(blk.w), c1);
      }
    }
    part[ks * HID + h] = c0 + c1;
    __syncthreads();   // B2

    if (ks == 0) {
      float ca = a2 + bhv + part[h] + part[HID + h];
      float c  = fast_tanh(ca);
      float hn = fmaf(g, phv, (1.f - g) * c);
      float nb = __shfl_xor(hn, 1, 64);   // DPP xor-1
      if ((h & 1) == 0) {                 // handoff store FIRST (children poll this)
        __hip_atomic_store(&HpkU[(size_t)i * (HID / 2) + (h >> 1)],
                           __builtin_bit_cast(unsigned, pkrtz(hn, nb)),
                           __ATOMIC_RELAXED, __HIP_MEMORY_SCOPE_AGENT);
      }
      H[(size_t)i * HID + h] = hn;        // fp32 row for leafmax (off critical path)
    }
    // no publish barrier, no waitcnt, no flag: the row stores are the signal
  }
}

// ---------------------------------------------------------------- leaf max partial (64 blocks x 32 leaves)
__global__ void leafmax_kernel(const float* __restrict__ H, const int* __restrict__ leafs,
                               float* __restrict__ partial) {
  int b = blockIdx.x;
  int h = threadIdx.x;
  float m = -INFINITY;
#pragma unroll 4
  for (int j = 0; j < N_LEAF / 64; ++j) {
    int node = leafs[b * (N_LEAF / 64) + j];
    m = fmaxf(m, H[(size_t)node * HID + h]);
  }
  partial[b * HID + h] = m;
}

// ---------------------------------------------------------------- final: reduce partials, W_out, softmax, loss
__global__ void final_kernel(const float* __restrict__ partial, const float* __restrict__ W_out,
                             const float* __restrict__ b_out, const float* __restrict__ y,
                             float* __restrict__ out) {
  int h = threadIdx.x;
  float m = -INFINITY;
#pragma unroll 8
  for (int b = 0; b < 64; ++b) m = fmaxf(m, partial[b * HID + h]);
  __shared__ float fs[HID];
  __shared__ float red[HID];
  __shared__ float logit[NCLASS];
  fs[h] = m;
  __syncthreads();
  for (int c = 0; c < NCLASS; ++c) {
    red[h] = W_out[c * HID + h] * fs[h];
    __syncthreads();
    for (int s = HID / 2; s > 0; s >>= 1) {
      if (h < s) red[h] += red[h + s];
      __syncthreads();
    }
    if (h == 0) logit[c] = red[0] + b_out[c];
    __syncthreads();
  }
  if (h == 0) {
    float mx = logit[0];
    for (int c = 1; c < NCLASS; ++c) mx = fmaxf(mx, logit[c]);
    float e[NCLASS], s = 0.f;
    for (int c = 0; c < NCLASS; ++c) { e[c] = expf(logit[c] - mx); s += e[c]; }
    float loss = 0.f;
    for (int c = 0; c < NCLASS; ++c) {
      float p = e[c] / s;
      out[c] = p;
      float d = y[c] - p;
      loss += d * d;
    }
    out[NCLASS] = loss;
  }
}

// ---------------------------------------------------------------- launch
extern "C" void kernel_launch(void* const* d_in, const int* in_sizes, int n_in,
                              void* d_out, int out_size, void* d_ws, size_t ws_size,
                              hipStream_t stream) {
  const int*   tree = (const int*)d_in[0];
  const int*   edge = (const int*)d_in[1];
  const int*   leaf = (const int*)d_in[2];
  const float* y    = (const float*)d_in[3];
  const float* E    = (const float*)d_in[4];
  const float* Wz   = (const float*)d_in[5];
  const float* Uz   = (const float*)d_in[6];
  const float* bz   = (const float*)d_in[7];
  const float* Wr   = (const float*)d_in[8];
  const float* Ur   = (const float*)d_in[9];
  const float* br   = (const float*)d_in[10];
  const float* Wh   = (const float*)d_in[11];
  const float* Uh   = (const float*)d_in[12];
  const float* bh   = (const float*)d_in[13];
  const float* Wout = (const float*)d_in[14];
  const float* bout = (const float*)d_in[15];
  float* out = (float*)d_out;

  char* base = (char*)d_ws;
  size_t b = 0;
  _Float16* ETh = (_Float16*)(base + b); b += (size_t)VOCAB * HID * 2;      // 25.7 MB
  b = (b + 255) & ~(size_t)255;
  half2_t* Upk = (half2_t*)(base + b); b += (size_t)3 * 4 * 8192 * 4;       // 98304 half2
  half2_t* Hpk = (half2_t*)(base + b); b += (size_t)N_NODES * (HID / 2) * 4;
  float* X   = (float*)(base + b); b += (size_t)N_NODES * HID * 4;
  float* Az  = (float*)(base + b); b += (size_t)N_NODES * HID * 4;
  float* Ar  = (float*)(base + b); b += (size_t)N_NODES * HID * 4;
  float* Ah  = (float*)(base + b); b += (size_t)N_NODES * HID * 4;
  float* H   = (float*)(base + b); b += (size_t)N_NODES * HID * 4;
  float* partial = (float*)(base + b); b += (size_t)64 * HID * 4;

  poison_hpk_kernel<<<(N_NODES * (HID / 2) + 255) / 256, 256, 0, stream>>>((unsigned*)Hpk);
  transpose_f16_kernel<<<dim3((VOCAB + 31) / 32, HID / 32), dim3(32, 8), 0, stream>>>(E, ETh, HID, VOCAB);
  pack_u_kernel<<<12, 256, 0, stream>>>(Uz, Ur, Uh, Upk);
  gather_x_kernel<<<N_NODES, 128, 0, stream>>>(tree, (const half2_t*)ETh, X, H, Hpk);
  gemm3_kernel<<<dim3(N_NODES / 64, HID / 64, 3), 256, 0, stream>>>(X, Wz, Wr, Wh, Az, Ar, Ah);
  rnn_kernel<<<RNN_BLOCKS, 512, 0, stream>>>(Az, Ar, Ah, Upk, bz, br, bh, edge, H, (unsigned*)Hpk);
  leafmax_kernel<<<64, HID, 0, stream>>>(H, leaf, partial);
  final_kernel<<<1, HID, 0, stream>>>(partial, Wout, bout, y, out);
}